// Round 4
// baseline (512.705 us; speedup 1.0000x reference)
//
#include <hip/hip_runtime.h>
#include <stdint.h>

typedef unsigned short u16;
typedef unsigned int u32;
typedef __attribute__((ext_vector_type(8))) short short8;
typedef __attribute__((ext_vector_type(4))) float f32x4;
typedef __attribute__((ext_vector_type(4))) u32 u32x4;

#define B_ 8
#define N_ 8192
#define M_ 2048
#define DD 256
#define KENC 32

// consts layout (float offsets)
#define SC1 0
#define SH1 256
#define SC2 512
#define SH2 768
#define C2OFF 1024
#define SOFF 1056
#define RNOFF 1088

// ws offsets (bytes)
#define OFF_IDX3   0ull
#define OFF_W3     786432ull
#define OFF_FT     1572864ull
#define OFF_H1T    68681728ull     // Epart aliases this region after GEMM2
#define OFF_ERELU  102236160ull
#define OFF_PART   102498304ull
#define OFF_CONSTS 102760448ull
#define OFF_CTX    102768640ull
#define OFF_W1D    102776832ull
#define OFF_W2D    103038976ull
#define OFF_CWD    103170048ull
#define OFF_FLAG   103186432ull

__device__ __forceinline__ float bf2f(u16 v){ return __uint_as_float(((u32)v)<<16); }
__device__ __forceinline__ u16 f2bf(float f){
  u32 x = __float_as_uint(f);
  return (u16)((x + 0x7FFFu + ((x>>16)&1u)) >> 16);
}
// dtype-adaptive scalar load: flag=1 -> fp32 buffer, flag=0 -> bf16 buffer
__device__ __forceinline__ float ldf(const void* p, size_t i, int f){
  return f ? ((const float*)p)[i] : bf2f(((const u16*)p)[i]);
}

// ---------------- D: runtime dtype detection from bn_v1 (uniform(0.5,1.5)) ----------------
__global__ __launch_bounds__(256) void k_detect(const void* v1, int* flagp){
  __shared__ int cntb, cntf;
  int t = threadIdx.x;
  if (t==0){ cntb=0; cntf=0; }
  __syncthreads();
  float vb = bf2f(((const u16*)v1)[t]);
  if (!(vb > 0.4f && vb < 1.6f)) atomicAdd(&cntb, 1);
  if (t < 64){
    float vf = ((const float*)v1)[t];
    if (!(vf > 0.4f && vf < 1.6f)) atomicAdd(&cntf, 1);
  }
  __syncthreads();
  if (t==0) flagp[0] = (cntb > 0 && cntf == 0) ? 1 : 0;
}

// ---------------- C: convert w1/w2/cw to bf16 ws copies ----------------
__global__ __launch_bounds__(256) void k_convert(
    const void* w1, const void* w2, const void* cwsrc, const int* __restrict__ flagp,
    u16* __restrict__ W1d, u16* __restrict__ W2d, u16* __restrict__ CWd){
  int id = blockIdx.x*256 + threadIdx.x;
  int f = flagp[0];
  if (id < 131072){
    W1d[id] = f ? f2bf(((const float*)w1)[id]) : ((const u16*)w1)[id];
  } else if (id < 196608){
    int j = id - 131072;
    W2d[j] = f ? f2bf(((const float*)w2)[j]) : ((const u16*)w2)[j];
  } else if (id < 204800){
    int j = id - 196608;
    CWd[j] = f ? f2bf(((const float*)cwsrc)[j]) : ((const u16*)cwsrc)[j];
  }
}

// ---------------- K0: fold BN params, codeword norms ----------------
__global__ __launch_bounds__(256) void k0_setup(
    const void* cb1, const void* g1, const void* be1, const void* m1, const void* v1,
    const void* cb2, const void* g2, const void* be2, const void* m2, const void* v2,
    const u16* __restrict__ CWd, const void* es, const int* __restrict__ flagp,
    float* __restrict__ consts){
  int t = threadIdx.x;
  int f = flagp[0];
  {
    float g = ldf(g1,t,f), be = ldf(be1,t,f), m = ldf(m1,t,f), v = ldf(v1,t,f), cb = ldf(cb1,t,f);
    float r = 1.f/sqrtf(v + 1e-5f);
    float sc = g*r;
    consts[SC1+t] = sc; consts[SH1+t] = (cb-m)*sc + be;
  }
  {
    float g = ldf(g2,t,f), be = ldf(be2,t,f), m = ldf(m2,t,f), v = ldf(v2,t,f), cb = ldf(cb2,t,f);
    float r = 1.f/sqrtf(v + 1e-5f);
    float sc = g*r;
    consts[SC2+t] = sc; consts[SH2+t] = (cb-m)*sc + be;
  }
  if (t < KENC){
    float s = 0.f;
    for (int d=0; d<DD; d++){ float c = bf2f(CWd[t*DD+d]); s = fmaf(c,c,s); }
    consts[C2OFF+t] = s;
    consts[SOFF+t]  = ldf(es,t,f);
  }
}

// ---------------- K1: three_nn, interleaved 4-slice scan, 2 queries/thread ----------------
// slice sl handles candidates m == sl (mod 4): wave reads 4 consecutive float4s
// per step -> 16 distinct banks, conflict-free broadcast.
__global__ __launch_bounds__(256) void k1_three_nn(
    const void* unknown, const void* known, const int* __restrict__ flagp,
    int* __restrict__ idx3, float* __restrict__ w3){
  __shared__ float4 kp[M_];
  int b = blockIdx.y, t = threadIdx.x;
  int f = flagp[0];
  for (int i=t; i<M_; i+=256){
    size_t o = ((size_t)b*M_ + i)*3;
    float x = ldf(known,o,f), y = ldf(known,o+1,f), z = ldf(known,o+2,f);
    float y2 = __fadd_rn(__fadd_rn(__fmul_rn(x,x), __fmul_rn(y,y)), __fmul_rn(z,z));
    kp[i] = make_float4(x,y,z,y2);
  }
  __syncthreads();
  int qq = t >> 2, sl = t & 3;       // 64 thread-quads; each thread: 2 queries, 1 slice
  int pid0 = blockIdx.x*128 + qq;    // query 0
  int pid1 = pid0 + 64;              // query 1
  float ux[2], uy[2], uz[2], x2[2];
  #pragma unroll
  for (int qi=0; qi<2; qi++){
    size_t uo = ((size_t)b*N_ + (qi ? pid1 : pid0))*3;
    ux[qi]=ldf(unknown,uo,f); uy[qi]=ldf(unknown,uo+1,f); uz[qi]=ldf(unknown,uo+2,f);
    x2[qi] = __fadd_rn(__fadd_rn(__fmul_rn(ux[qi],ux[qi]), __fmul_rn(uy[qi],uy[qi])), __fmul_rn(uz[qi],uz[qi]));
  }
  float b0[2], b1[2], b2v[2];
  int i0[2], i1[2], i2[2];
  #pragma unroll
  for (int qi=0; qi<2; qi++){ b0[qi]=3.4e38f; b1[qi]=3.4e38f; b2v[qi]=3.4e38f; i0[qi]=-1; i1[qi]=-1; i2[qi]=-1; }
  for (int mm=0; mm<128; mm++){
    #pragma unroll
    for (int u=0; u<4; u++){
      int m = mm*16 + u*4 + sl;
      float4 km = kp[m];
      #pragma unroll
      for (int qi=0; qi<2; qi++){
        float dotv = __fadd_rn(__fadd_rn(__fmul_rn(ux[qi],km.x), __fmul_rn(uy[qi],km.y)), __fmul_rn(uz[qi],km.z));
        float d2 = __fadd_rn(__fsub_rn(x2[qi], __fmul_rn(2.f,dotv)), km.w);
        if (d2 < b2v[qi]){
          if (d2 < b0[qi]){ b2v[qi]=b1[qi];i2[qi]=i1[qi]; b1[qi]=b0[qi];i1[qi]=i0[qi]; b0[qi]=d2;i0[qi]=m; }
          else if (d2 < b1[qi]){ b2v[qi]=b1[qi];i2[qi]=i1[qi]; b1[qi]=d2;i1[qi]=m; }
          else { b2v[qi]=d2; i2[qi]=m; }
        }
      }
    }
  }
  // merge sorted triples across the 4 slice-lanes (stable by (d, idx))
  #pragma unroll
  for (int delta=1; delta<=2; delta<<=1){
    #pragma unroll
    for (int qi=0; qi<2; qi++){
      float o0=__shfl_xor(b0[qi],delta,64), o1=__shfl_xor(b1[qi],delta,64), o2=__shfl_xor(b2v[qi],delta,64);
      int   j0=__shfl_xor(i0[qi],delta,64), j1=__shfl_xor(i1[qi],delta,64), j2=__shfl_xor(i2[qi],delta,64);
      float dv[3] = {o0,o1,o2}; int jv[3] = {j0,j1,j2};
      #pragma unroll
      for (int e=0; e<3; e++){
        float dd = dv[e]; int jj = jv[e];
        bool lt2 = (dd < b2v[qi]) || (dd == b2v[qi] && jj < i2[qi]);
        if (lt2){
          bool lt0 = (dd < b0[qi]) || (dd == b0[qi] && jj < i0[qi]);
          bool lt1 = (dd < b1[qi]) || (dd == b1[qi] && jj < i1[qi]);
          if (lt0){ b2v[qi]=b1[qi];i2[qi]=i1[qi]; b1[qi]=b0[qi];i1[qi]=i0[qi]; b0[qi]=dd;i0[qi]=jj; }
          else if (lt1){ b2v[qi]=b1[qi];i2[qi]=i1[qi]; b1[qi]=dd;i1[qi]=jj; }
          else { b2v[qi]=dd; i2[qi]=jj; }
        }
      }
    }
  }
  if (sl == 0){
    #pragma unroll
    for (int qi=0; qi<2; qi++){
      float da = __fsqrt_rn(fmaxf(b0[qi],1e-12f));
      float db = __fsqrt_rn(fmaxf(b1[qi],1e-12f));
      float dc = __fsqrt_rn(fmaxf(b2v[qi],1e-12f));
      float r0 = __fdiv_rn(1.f, __fadd_rn(da,1e-8f));
      float r1 = __fdiv_rn(1.f, __fadd_rn(db,1e-8f));
      float r2 = __fdiv_rn(1.f, __fadd_rn(dc,1e-8f));
      float rs = __fadd_rn(__fadd_rn(r0,r1),r2);
      size_t o = ((size_t)b*N_ + (qi ? pid1 : pid0))*3;
      idx3[o]=i0[qi]; idx3[o+1]=i1[qi]; idx3[o+2]=i2[qi];
      w3[o]=__fdiv_rn(r0,rs); w3[o+1]=__fdiv_rn(r1,rs); w3[o+2]=__fdiv_rn(r2,rs);
    }
  }
}

// ---------------- K2: three_interpolate -> Ft[:, :, 0:256] (point-major) ----------------
__global__ __launch_bounds__(256) void k2_interp(
    const void* kf, const int* __restrict__ idx3,
    const float* __restrict__ w3, const int* __restrict__ flagp, u16* __restrict__ Ft){
  __shared__ u16 Ls[M_*8]; // [i][c], 32KB
  int ct = blockIdx.x;  // 0..31 (channel tile of 8)
  int rg = blockIdx.y;  // 0..3 (rep group)
  int b = blockIdx.z, t = threadIdx.x;
  int f = flagp[0];
  for (int cp=0; cp<4; cp++){
    int c0 = ct*8 + cp*2;
    size_t base0 = ((size_t)b*DD + c0)*M_;
    size_t base1 = base0 + M_;
    for (int i=t; i<M_; i+=256){
      float f0 = ldf(kf, base0+i, f);
      float f1 = ldf(kf, base1+i, f);
      u32 w = (u32)f2bf(f0) | ((u32)f2bf(f1)<<16);
      *(u32*)(Ls + i*8 + cp*2) = w;
    }
  }
  __syncthreads();
  for (int rep=rg*8; rep<rg*8+8; rep++){
    int pid = rep*256 + t;
    size_t o3 = ((size_t)b*N_ + pid)*3;
    int ia = idx3[o3], ib = idx3[o3+1], ic = idx3[o3+2];
    float wa = w3[o3], wb = w3[o3+1], wc = w3[o3+2];
    short8 va = *(const short8*)(Ls + ia*8);
    short8 vb = *(const short8*)(Ls + ib*8);
    short8 vc = *(const short8*)(Ls + ic*8);
    u32x4 pk;
    #pragma unroll
    for (int cq=0; cq<4; cq++){
      float fa0 = bf2f((u16)va[cq*2]),   fb0 = bf2f((u16)vb[cq*2]),   fc0 = bf2f((u16)vc[cq*2]);
      float fa1 = bf2f((u16)va[cq*2+1]), fb1 = bf2f((u16)vb[cq*2+1]), fc1 = bf2f((u16)vc[cq*2+1]);
      float v0 = fmaf(wc, fc0, fmaf(wb, fb0, wa*fa0));
      float v1 = fmaf(wc, fc1, fmaf(wb, fb1, wa*fa1));
      pk[cq] = (u32)f2bf(v0) | ((u32)f2bf(v1)<<16);
    }
    *(u32x4*)(Ft + ((size_t)b*N_ + pid)*512 + ct*8) = pk;
  }
}

// ---------------- K2b: transpose unknow_feats -> Ft[:, :, 256:512] ----------------
__global__ __launch_bounds__(256) void k2b_transpose_uf(
    const void* uf, const int* __restrict__ flagp, u16* __restrict__ Ft){
  __shared__ u16 Ls[64*72];
  int bx = blockIdx.x, cy = blockIdx.y, b = blockIdx.z, t = threadIdx.x;
  int f = flagp[0];
  {
    int n = t & 63, cg = t >> 6;
    for (int i=0; i<16; i++){
      int c = cg*16 + i;
      Ls[n*72 + c] = f2bf(ldf(uf, ((size_t)b*DD + cy*64 + c)*N_ + bx*64 + n, f));
    }
  }
  __syncthreads();
  int nl = t>>2, cc = t&3;
  u16* dst = Ft + ((size_t)b*N_ + bx*64 + nl)*512 + 256 + cy*64 + cc*16;
  *(u32x4*)dst     = *(const u32x4*)(Ls + nl*72 + cc*16);
  *(u32x4*)(dst+8) = *(const u32x4*)(Ls + nl*72 + cc*16 + 8);
}

// ---------------- K3/K4: MFMA GEMM + fused BN + ReLU, point-major output ----------------
__global__ __launch_bounds__(256) void gemm_bn_relu(
    const u16* __restrict__ W, const u16* __restrict__ Fin,
    const float* __restrict__ consts, int sc_off, int sh_off,
    u16* __restrict__ Out, int K){
  __shared__ u16 SM[17408]; // As(4096)+Bs(4096) in K-loop; Cs(128x136) in epilogue
  u16* As = SM; u16* Bs = SM + 4096;
  int b = blockIdx.z, ot = blockIdx.y*128, nt = blockIdx.x*128;
  int t = threadIdx.x, wave = t>>6, lane = t&63, ln = lane&15, quad = lane>>4;
  int wo = (wave&1)*64, wn = (wave>>1)*64;
  f32x4 acc[4][4];
  #pragma unroll
  for (int i=0;i<4;i++)
    #pragma unroll
    for (int j=0;j<4;j++) acc[i][j] = (f32x4)0.f;
  const u16* Wp = W + (size_t)ot*K;
  const u16* Fp = Fin + ((size_t)b*N_ + nt)*K;
  for (int kk=0; kk<K; kk+=32){
    #pragma unroll
    for (int i=0;i<2;i++){
      int ch = t*2 + i;
      int r = ch>>2, kc = (ch&3)*8;
      *(u32x4*)(As + r*32 + kc) = *(const u32x4*)(Wp + (size_t)r*K + kk + kc);
      *(u32x4*)(Bs + r*32 + kc) = *(const u32x4*)(Fp + (size_t)r*K + kk + kc);
    }
    __syncthreads();
    short8 af[4], bfr[4];
    #pragma unroll
    for (int i=0;i<4;i++) af[i]  = *(const short8*)(As + (wo+i*16+ln)*32 + quad*8);
    #pragma unroll
    for (int j=0;j<4;j++) bfr[j] = *(const short8*)(Bs + (wn+j*16+ln)*32 + quad*8);
    #pragma unroll
    for (int i=0;i<4;i++)
      #pragma unroll
      for (int j=0;j<4;j++)
        acc[i][j] = __builtin_amdgcn_mfma_f32_16x16x32_bf16(af[i], bfr[j], acc[i][j], 0,0,0);
    __syncthreads();
  }
  u16* Cs = SM; // stride 136
  #pragma unroll
  for (int i=0;i<4;i++){
    #pragma unroll
    for (int r=0;r<4;r++){
      int ol = wo + i*16 + quad*4 + r;
      float sc = consts[sc_off + ot + ol], sh = consts[sh_off + ot + ol];
      #pragma unroll
      for (int j=0;j<4;j++){
        float v = fmaxf(fmaf(acc[i][j][r], sc, sh), 0.f);
        Cs[(wn + j*16 + ln)*136 + ol] = f2bf(v);
      }
    }
  }
  __syncthreads();
  int nl = t>>1, half = t&1;
  u16* dst = Out + ((size_t)b*N_ + nt + nl)*256 + ot + half*64;
  const u16* srcr = Cs + nl*136 + half*64;
  #pragma unroll
  for (int c=0;c<8;c++)
    *(u32x4*)(dst + c*8) = *(const u32x4*)(srcr + c*8);
}

// ---------------- K5: encoding partials ----------------
__global__ __launch_bounds__(256) void k5_enc_partial(
    const u16* __restrict__ X, const u16* __restrict__ cw,
    const float* __restrict__ consts, float* __restrict__ Epart){
  __shared__ u16 Xs[64*264];
  __shared__ float A_lds[64*32];
  __shared__ float xn2s[64];
  int g = blockIdx.x, b = blockIdx.y, t = threadIdx.x;
  int wave = t>>6, lane = t&63, ln = lane&15, quad = lane>>4;
  int tk = t>>3, tg = t&7;
  float accE[32];
  #pragma unroll
  for (int p=0;p<32;p++) accE[p]=0.f;
  float asum = 0.f;
  float c2v0 = consts[C2OFF + ln], c2v1 = consts[C2OFF + 16 + ln];
  float sv0  = consts[SOFF + ln],  sv1  = consts[SOFF + 16 + ln];
  for (int tt=0; tt<2; tt++){
    int n0 = (g*2+tt)*64;
    const u16* Xp = X + ((size_t)b*N_ + n0)*256;
    #pragma unroll
    for (int i=0;i<8;i++){
      int ch = t + i*256;
      int r = ch>>5, kc = (ch&31)*8;
      *(u32x4*)(Xs + r*264 + kc) = *(const u32x4*)(Xp + r*256 + kc);
    }
    __syncthreads();
    if (t < 64){
      const u16* row = Xs + t*264;
      float s = 0.f;
      for (int d=0; d<256; d+=8){
        short8 xv = *(const short8*)(row + d);
        #pragma unroll
        for (int q=0;q<8;q++){ float x = bf2f((u16)xv[q]); s = fmaf(x,x,s); }
      }
      xn2s[t] = s;
    }
    __syncthreads();
    f32x4 pj0 = (f32x4)0.f, pj1 = (f32x4)0.f;
    const u16* xrow = Xs + (wave*16 + ln)*264;
    #pragma unroll
    for (int kk=0; kk<256; kk+=32){
      short8 a   = *(const short8*)(xrow + kk + quad*8);
      short8 bf0 = *(const short8*)(cw + (size_t)ln*256 + kk + quad*8);
      short8 bf1 = *(const short8*)(cw + (size_t)(16+ln)*256 + kk + quad*8);
      pj0 = __builtin_amdgcn_mfma_f32_16x16x32_bf16(a, bf0, pj0, 0,0,0);
      pj1 = __builtin_amdgcn_mfma_f32_16x16x32_bf16(a, bf1, pj1, 0,0,0);
    }
    #pragma unroll
    for (int r=0;r<4;r++){
      int nl = wave*16 + quad*4 + r;
      float xv = xn2s[nl];
      float v0 = sv0 * __fadd_rn(__fsub_rn(xv, __fmul_rn(2.f,pj0[r])), c2v0);
      float v1 = sv1 * __fadd_rn(__fsub_rn(xv, __fmul_rn(2.f,pj1[r])), c2v1);
      float mx = fmaxf(v0,v1);
      #pragma unroll
      for (int d=1; d<16; d<<=1) mx = fmaxf(mx, __shfl_xor(mx, d, 64));
      float e0 = __expf(v0-mx), e1 = __expf(v1-mx);
      float es = e0+e1;
      #pragma unroll
      for (int d=1; d<16; d<<=1) es += __shfl_xor(es, d, 64);
      float inv = 1.f/es;
      A_lds[nl*32 + ln]      = e0*inv;
      A_lds[nl*32 + 16 + ln] = e1*inv;
    }
    __syncthreads();
    #pragma unroll 2
    for (int n=0; n<64; n++){
      float a = A_lds[n*32 + tk];
      asum += a;
      const u16* xr = Xs + n*264 + tg*32;
      #pragma unroll
      for (int p8=0; p8<4; p8++){
        u32x4 xv = *(const u32x4*)(xr + p8*8);
        #pragma unroll
        for (int q=0; q<4; q++){
          u32 w = xv[q];
          float lo = __uint_as_float(w<<16);
          float hi = __uint_as_float(w & 0xffff0000u);
          accE[p8*8 + q*2]   = fmaf(a, lo, accE[p8*8 + q*2]);
          accE[p8*8 + q*2+1] = fmaf(a, hi, accE[p8*8 + q*2+1]);
        }
      }
    }
    __syncthreads();
  }
  int slab = b*64 + g;
  float* Ed = Epart + (size_t)slab*8224 + (size_t)tk*257;
  #pragma unroll
  for (int p=0;p<32;p++) Ed[tg*32 + p] = accE[p];
  if (tg==0) Ed[256] = asum;
}

// ---------------- K5b: reduce slabs, subtract asum*cw, relu ----------------
__global__ __launch_bounds__(256) void k5b_reduce(
    const float* __restrict__ Epart, const u16* __restrict__ cw, float* __restrict__ Erelu){
  int id = blockIdx.x*256 + threadIdx.x;
  int d = id & 255, k = (id>>8)&31, b = id>>13;
  float s = 0.f, as = 0.f;
  for (int sl=0; sl<64; sl++){
    const float* Ep = Epart + ((size_t)(b*64+sl))*8224 + (size_t)k*257;
    s  += Ep[d];
    as += Ep[256];
  }
  float cv = bf2f(cw[k*256+d]);
  Erelu[(size_t)b*8192 + k*256 + d] = fmaxf(s - as*cv, 0.f);
}

// ---------------- K6a: per-batch L2 norm ----------------
__global__ __launch_bounds__(256) void k6a_norm(
    const float* __restrict__ Erelu, float* __restrict__ consts){
  __shared__ float red[256];
  int b = blockIdx.x, t = threadIdx.x;
  float s = 0.f;
  for (int i=0;i<32;i++){ float e = Erelu[(size_t)b*8192 + i*256 + t]; s = fmaf(e,e,s); }
  red[t] = s; __syncthreads();
  for (int w=128; w>0; w>>=1){ if (t<w) red[t] += red[t+w]; __syncthreads(); }
  if (t==0) consts[RNOFF + b] = 1.f/fmaxf(__fsqrt_rn(red[0]), 1e-12f);
}

// ---------------- K6b: linear partial dots ----------------
__global__ __launch_bounds__(256) void k6b_partial(
    const float* __restrict__ Erelu, const void* lw, const int* __restrict__ flagp,
    float* __restrict__ partials){
  __shared__ float Er[256];
  int kc = blockIdx.x, b = blockIdx.y, t = threadIdx.x;
  int f = flagp[0];
  Er[t] = Erelu[(size_t)b*8192 + kc*256 + t];
  __syncthreads();
  float s = 0.f;
  if (f){
    const float* lwp = (const float*)lw + (size_t)t*8192 + kc*256;
    for (int p=0; p<256; p+=4){
      f32x4 v = *(const f32x4*)(lwp + p);
      #pragma unroll
      for (int q=0;q<4;q++) s = fmaf(Er[p+q], v[q], s);
    }
  } else {
    const u16* lwp = (const u16*)lw + (size_t)t*8192 + kc*256;
    for (int p=0; p<256; p+=8){
      u32x4 v = *(const u32x4*)(lwp + p);
      #pragma unroll
      for (int q=0;q<4;q++){
        u32 w = v[q];
        s = fmaf(Er[p+q*2],   __uint_as_float(w<<16), s);
        s = fmaf(Er[p+q*2+1], __uint_as_float(w & 0xffff0000u), s);
      }
    }
  }
  partials[((size_t)b*32 + kc)*256 + t] = s;
}

// ---------------- K6c: ctx = sigmoid(rnorm*dot + bias) ----------------
__global__ __launch_bounds__(256) void k6c_ctx(
    const float* __restrict__ partials, const float* __restrict__ consts,
    const void* lb, const int* __restrict__ flagp, float* __restrict__ ctx){
  int b = blockIdx.x, t = threadIdx.x;
  int f = flagp[0];
  float s = 0.f;
  for (int kc=0; kc<32; kc++) s += partials[((size_t)b*32+kc)*256 + t];
  float x = fmaf(consts[RNOFF+b], s, ldf(lb,t,f));
  ctx[b*256 + t] = 1.f/(1.f + __expf(-x));
}

// ---------------- K7: out[b][o][n] = ht[b][n][o] * ctx[b][o] ----------------
__global__ __launch_bounds__(256) void k7_out(
    const u16* __restrict__ ht, const float* __restrict__ ctx,
    const int* __restrict__ flagp, void* out){
  __shared__ u16 Ls[64*72];
  int bx = blockIdx.x, oy = blockIdx.y, b = blockIdx.z, t = threadIdx.x;
  int f = flagp[0];
  {
    int nl = t>>2, oc = t&3;
    const u16* src = ht + ((size_t)b*N_ + bx*64 + nl)*256 + oy*64 + oc*16;
    *(u32x4*)(Ls + nl*72 + oc*16)     = *(const u32x4*)src;
    *(u32x4*)(Ls + nl*72 + oc*16 + 8) = *(const u32x4*)(src + 8);
  }
  __syncthreads();
  int ol = t>>2, nc = t&3;
  float cv = ctx[b*256 + oy*64 + ol];
  size_t dstoff = ((size_t)b*DD + oy*64 + ol)*N_ + bx*64 + nc*16;
  if (f){
    float* dst = (float*)out + dstoff;
    #pragma unroll
    for (int wq=0; wq<4; wq++){
      f32x4 v;
      #pragma unroll
      for (int q=0;q<4;q++) v[q] = bf2f(Ls[(nc*16 + wq*4 + q)*72 + ol]) * cv;
      *(f32x4*)(dst + wq*4) = v;
    }
  } else {
    u32 words[8];
    #pragma unroll
    for (int wq=0; wq<8; wq++){
      float v0 = bf2f(Ls[(nc*16 + wq*2)*72 + ol]) * cv;
      float v1 = bf2f(Ls[(nc*16 + wq*2+1)*72 + ol]) * cv;
      words[wq] = (u32)f2bf(v0) | ((u32)f2bf(v1)<<16);
    }
    u16* dst = (u16*)out + dstoff;
    u32x4 w0 = {words[0],words[1],words[2],words[3]};
    u32x4 w1 = {words[4],words[5],words[6],words[7]};
    *(u32x4*)dst     = w0;
    *(u32x4*)(dst+8) = w1;
  }
}

extern "C" void kernel_launch(void* const* d_in, const int* in_sizes, int n_in,
                              void* d_out, int out_size, void* d_ws, size_t ws_size,
                              hipStream_t stream){
  const void* unknown = d_in[0];
  const void* known   = d_in[1];
  const void* uf      = d_in[2];
  const void* kf      = d_in[3];
  const void* w1      = d_in[4];
  const void* cb1     = d_in[5];
  const void* g1      = d_in[6];
  const void* be1     = d_in[7];
  const void* m1      = d_in[8];
  const void* v1      = d_in[9];
  const void* w2      = d_in[10];
  const void* cb2     = d_in[11];
  const void* g2      = d_in[12];
  const void* be2     = d_in[13];
  const void* m2      = d_in[14];
  const void* v2      = d_in[15];
  const void* cw      = d_in[16];
  const void* es      = d_in[17];
  const void* lw      = d_in[18];
  const void* lb      = d_in[19];

  char* ws = (char*)d_ws;
  int*   idx3  = (int*)(ws + OFF_IDX3);
  float* w3    = (float*)(ws + OFF_W3);
  u16*   Ft    = (u16*)(ws + OFF_FT);
  u16*   ht    = Ft;                       // alias: Ft dead after GEMM1 consumes it
  u16*   h1t   = (u16*)(ws + OFF_H1T);
  float* Epart = (float*)(ws + OFF_H1T);   // alias: h1t dead after GEMM2
  float* Erelu    = (float*)(ws + OFF_ERELU);
  float* partials = (float*)(ws + OFF_PART);
  float* consts   = (float*)(ws + OFF_CONSTS);
  float* ctx      = (float*)(ws + OFF_CTX);
  u16*   W1d   = (u16*)(ws + OFF_W1D);
  u16*   W2d   = (u16*)(ws + OFF_W2D);
  u16*   CWd   = (u16*)(ws + OFF_CWD);
  int*   flagp = (int*)(ws + OFF_FLAG);

  k_detect<<<1, 256, 0, stream>>>(v1, flagp);
  k_convert<<<800, 256, 0, stream>>>(w1, w2, cw, flagp, W1d, W2d, CWd);
  k0_setup<<<1, 256, 0, stream>>>(cb1,g1,be1,m1,v1, cb2,g2,be2,m2,v2, CWd, es, flagp, consts);
  k1_three_nn<<<dim3(64,8), 256, 0, stream>>>(unknown, known, flagp, idx3, w3);
  k2_interp<<<dim3(32,4,8), 256, 0, stream>>>(kf, idx3, w3, flagp, Ft);
  k2b_transpose_uf<<<dim3(128,4,8), 256, 0, stream>>>(uf, flagp, Ft);
  gemm_bn_relu<<<dim3(64,2,8), 256, 0, stream>>>(W1d, Ft,  consts, SC1, SH1, h1t, 512);
  gemm_bn_relu<<<dim3(64,2,8), 256, 0, stream>>>(W2d, h1t, consts, SC2, SH2, ht,  256);
  k5_enc_partial<<<dim3(64,8), 256, 0, stream>>>(ht, CWd, consts, Epart);
  k5b_reduce<<<256, 256, 0, stream>>>(Epart, CWd, Erelu);
  k6a_norm<<<8, 256, 0, stream>>>(Erelu, consts);
  k6b_partial<<<dim3(32,8), 256, 0, stream>>>(Erelu, lw, flagp, partials);
  k6c_ctx<<<8, 256, 0, stream>>>(partials, consts, lb, flagp, ctx);
  k7_out<<<dim3(128,4,8), 256, 0, stream>>>(ht, ctx, flagp, d_out);
}

// Round 5
// 476.375 us; speedup vs baseline: 1.0763x; 1.0763x over previous
//
#include <hip/hip_runtime.h>
#include <stdint.h>

typedef unsigned short u16;
typedef unsigned int u32;
typedef __attribute__((ext_vector_type(8))) short short8;
typedef __attribute__((ext_vector_type(4))) float f32x4;
typedef __attribute__((ext_vector_type(4))) u32 u32x4;

#define B_ 8
#define N_ 8192
#define M_ 2048
#define DD 256
#define KENC 32

// consts layout (float offsets)
#define SC1 0
#define SH1 256
#define SC2 512
#define SH2 768
#define C2OFF 1024
#define SOFF 1056
#define RNOFF 1088

// ws offsets (bytes)
#define OFF_IDX3   0ull
#define OFF_W3     786432ull
#define OFF_FT     1572864ull
#define OFF_H1T    68681728ull     // Epart aliases this region after GEMM2
#define OFF_ERELU  102236160ull
#define OFF_PART   102498304ull
#define OFF_CONSTS 102760448ull
#define OFF_CTX    102768640ull
#define OFF_W1D    102776832ull
#define OFF_W2D    103038976ull
#define OFF_CWD    103170048ull
#define OFF_FLAG   103186432ull

__device__ __forceinline__ float bf2f(u16 v){ return __uint_as_float(((u32)v)<<16); }
__device__ __forceinline__ u16 f2bf(float f){
  u32 x = __float_as_uint(f);
  return (u16)((x + 0x7FFFu + ((x>>16)&1u)) >> 16);
}
__device__ __forceinline__ float ldf(const void* p, size_t i, int f){
  return f ? ((const float*)p)[i] : bf2f(((const u16*)p)[i]);
}
// async 16B global->LDS (wave-uniform lds base + lane*16)
__device__ __forceinline__ void gl_lds16(const u16* g, u16* l){
  __builtin_amdgcn_global_load_lds(
      (const __attribute__((address_space(1))) void*)g,
      (__attribute__((address_space(3))) void*)l, 16, 0, 0);
}

// ---------------- D: runtime dtype detection from bn_v1 (uniform(0.5,1.5)) ----------------
__global__ __launch_bounds__(256) void k_detect(const void* v1, int* flagp){
  __shared__ int cntb, cntf;
  int t = threadIdx.x;
  if (t==0){ cntb=0; cntf=0; }
  __syncthreads();
  float vb = bf2f(((const u16*)v1)[t]);
  if (!(vb > 0.4f && vb < 1.6f)) atomicAdd(&cntb, 1);
  if (t < 64){
    float vf = ((const float*)v1)[t];
    if (!(vf > 0.4f && vf < 1.6f)) atomicAdd(&cntf, 1);
  }
  __syncthreads();
  if (t==0) flagp[0] = (cntb > 0 && cntf == 0) ? 1 : 0;
}

// ---------------- C: convert w1/w2/cw to bf16 ws copies ----------------
__global__ __launch_bounds__(256) void k_convert(
    const void* w1, const void* w2, const void* cwsrc, const int* __restrict__ flagp,
    u16* __restrict__ W1d, u16* __restrict__ W2d, u16* __restrict__ CWd){
  int id = blockIdx.x*256 + threadIdx.x;
  int f = flagp[0];
  if (id < 131072){
    W1d[id] = f ? f2bf(((const float*)w1)[id]) : ((const u16*)w1)[id];
  } else if (id < 196608){
    int j = id - 131072;
    W2d[j] = f ? f2bf(((const float*)w2)[j]) : ((const u16*)w2)[j];
  } else if (id < 204800){
    int j = id - 196608;
    CWd[j] = f ? f2bf(((const float*)cwsrc)[j]) : ((const u16*)cwsrc)[j];
  }
}

// ---------------- K0: fold BN params, codeword norms ----------------
__global__ __launch_bounds__(256) void k0_setup(
    const void* cb1, const void* g1, const void* be1, const void* m1, const void* v1,
    const void* cb2, const void* g2, const void* be2, const void* m2, const void* v2,
    const u16* __restrict__ CWd, const void* es, const int* __restrict__ flagp,
    float* __restrict__ consts){
  int t = threadIdx.x;
  int f = flagp[0];
  {
    float g = ldf(g1,t,f), be = ldf(be1,t,f), m = ldf(m1,t,f), v = ldf(v1,t,f), cb = ldf(cb1,t,f);
    float r = 1.f/sqrtf(v + 1e-5f);
    float sc = g*r;
    consts[SC1+t] = sc; consts[SH1+t] = (cb-m)*sc + be;
  }
  {
    float g = ldf(g2,t,f), be = ldf(be2,t,f), m = ldf(m2,t,f), v = ldf(v2,t,f), cb = ldf(cb2,t,f);
    float r = 1.f/sqrtf(v + 1e-5f);
    float sc = g*r;
    consts[SC2+t] = sc; consts[SH2+t] = (cb-m)*sc + be;
  }
  if (t < KENC){
    float s = 0.f;
    for (int d=0; d<DD; d++){ float c = bf2f(CWd[t*DD+d]); s = fmaf(c,c,s); }
    consts[C2OFF+t] = s;
    consts[SOFF+t]  = ldf(es,t,f);
  }
}

// ---------------- K1: three_nn, 2-slice chains + branch-skipped insert ----------------
// lane pair (sl=0/1) scans m==sl (mod 2); chains of 1024 keep P(whole-wave skip) high
// so the expensive sorted-insert is s_cbranch_execz-skipped ~50% of steps.
__global__ __launch_bounds__(256) void k1_three_nn(
    const void* unknown, const void* known, const int* __restrict__ flagp,
    int* __restrict__ idx3, float* __restrict__ w3){
  __shared__ float4 kp[M_];
  int b = blockIdx.y, t = threadIdx.x;
  int f = flagp[0];
  for (int i=t; i<M_; i+=256){
    size_t o = ((size_t)b*M_ + i)*3;
    float x = ldf(known,o,f), y = ldf(known,o+1,f), z = ldf(known,o+2,f);
    float y2 = __fadd_rn(__fadd_rn(__fmul_rn(x,x), __fmul_rn(y,y)), __fmul_rn(z,z));
    kp[i] = make_float4(x,y,z,y2);
  }
  __syncthreads();
  int qq = t >> 1, sl = t & 1;       // 128 queries/block, 2 slices/query
  int pid = blockIdx.x*128 + qq;
  size_t uo = ((size_t)b*N_ + pid)*3;
  float ux=ldf(unknown,uo,f), uy=ldf(unknown,uo+1,f), uz=ldf(unknown,uo+2,f);
  float x2 = __fadd_rn(__fadd_rn(__fmul_rn(ux,ux), __fmul_rn(uy,uy)), __fmul_rn(uz,uz));
  // pre-doubled coords: fl(2a*b)=2*fl(a*b) and fl(2s+2t)=2*fl(s+t) exactly,
  // so (2ux*kx+2uy*ky)+2uz*kz == 2*dot bit-exactly vs the reference.
  float u2x = ux+ux, u2y = uy+uy, u2z = uz+uz;
  float b0=3.4e38f, b1=3.4e38f, b2v=3.4e38f;
  int i0=-1, i1=-1, i2=-1;
  for (int j0=0; j0<1024; j0+=4){
    float d[4]; int mi[4];
    #pragma unroll
    for (int u=0; u<4; u++){
      int m = (j0+u)*2 + sl;
      mi[u] = m;
      float4 km = kp[m];
      float dot2 = __fadd_rn(__fadd_rn(__fmul_rn(u2x,km.x), __fmul_rn(u2y,km.y)), __fmul_rn(u2z,km.z));
      d[u] = __fadd_rn(__fsub_rn(x2, dot2), km.w);
    }
    #pragma unroll
    for (int u=0; u<4; u++){
      float d2 = d[u];
      if (__builtin_expect(d2 < b2v, 0)){
        int m = mi[u];
        if (d2 < b0){ b2v=b1;i2=i1; b1=b0;i1=i0; b0=d2;i0=m; }
        else if (d2 < b1){ b2v=b1;i2=i1; b1=d2;i1=m; }
        else { b2v=d2; i2=m; }
      }
    }
  }
  // merge the two slice-lanes' sorted triples (stable by (d, idx))
  {
    float o0=__shfl_xor(b0,1,64), o1=__shfl_xor(b1,1,64), o2=__shfl_xor(b2v,1,64);
    int   j0=__shfl_xor(i0,1,64), j1=__shfl_xor(i1,1,64), j2=__shfl_xor(i2,1,64);
    float dv[3] = {o0,o1,o2}; int jv[3] = {j0,j1,j2};
    #pragma unroll
    for (int e=0; e<3; e++){
      float dd = dv[e]; int jj = jv[e];
      bool lt2 = (dd < b2v) || (dd == b2v && jj < i2);
      if (lt2){
        bool lt0 = (dd < b0) || (dd == b0 && jj < i0);
        bool lt1 = (dd < b1) || (dd == b1 && jj < i1);
        if (lt0){ b2v=b1;i2=i1; b1=b0;i1=i0; b0=dd;i0=jj; }
        else if (lt1){ b2v=b1;i2=i1; b1=dd;i1=jj; }
        else { b2v=dd; i2=jj; }
      }
    }
  }
  if (sl == 0){
    float da = __fsqrt_rn(fmaxf(b0,1e-12f));
    float db = __fsqrt_rn(fmaxf(b1,1e-12f));
    float dc = __fsqrt_rn(fmaxf(b2v,1e-12f));
    float r0 = __fdiv_rn(1.f, __fadd_rn(da,1e-8f));
    float r1 = __fdiv_rn(1.f, __fadd_rn(db,1e-8f));
    float r2 = __fdiv_rn(1.f, __fadd_rn(dc,1e-8f));
    float rs = __fadd_rn(__fadd_rn(r0,r1),r2);
    size_t o = ((size_t)b*N_ + pid)*3;
    idx3[o]=i0; idx3[o+1]=i1; idx3[o+2]=i2;
    w3[o]=__fdiv_rn(r0,rs); w3[o+1]=__fdiv_rn(r1,rs); w3[o+2]=__fdiv_rn(r2,rs);
  }
}

// ---------------- K2: three_interpolate -> Ft[:, :, 0:256] (point-major) ----------------
__global__ __launch_bounds__(256) void k2_interp(
    const void* kf, const int* __restrict__ idx3,
    const float* __restrict__ w3, const int* __restrict__ flagp, u16* __restrict__ Ft){
  __shared__ u16 Ls[M_*8]; // [i][c], 32KB
  int ct = blockIdx.x;  // 0..31 (channel tile of 8)
  int rg = blockIdx.y;  // 0..3 (rep group)
  int b = blockIdx.z, t = threadIdx.x;
  int f = flagp[0];
  for (int cp=0; cp<4; cp++){
    int c0 = ct*8 + cp*2;
    size_t base0 = ((size_t)b*DD + c0)*M_;
    size_t base1 = base0 + M_;
    for (int i=t; i<M_; i+=256){
      float f0 = ldf(kf, base0+i, f);
      float f1 = ldf(kf, base1+i, f);
      u32 w = (u32)f2bf(f0) | ((u32)f2bf(f1)<<16);
      *(u32*)(Ls + i*8 + cp*2) = w;
    }
  }
  __syncthreads();
  for (int rep=rg*8; rep<rg*8+8; rep++){
    int pid = rep*256 + t;
    size_t o3 = ((size_t)b*N_ + pid)*3;
    int ia = idx3[o3], ib = idx3[o3+1], ic = idx3[o3+2];
    float wa = w3[o3], wb = w3[o3+1], wc = w3[o3+2];
    short8 va = *(const short8*)(Ls + ia*8);
    short8 vb = *(const short8*)(Ls + ib*8);
    short8 vc = *(const short8*)(Ls + ic*8);
    u32x4 pk;
    #pragma unroll
    for (int cq=0; cq<4; cq++){
      float fa0 = bf2f((u16)va[cq*2]),   fb0 = bf2f((u16)vb[cq*2]),   fc0 = bf2f((u16)vc[cq*2]);
      float fa1 = bf2f((u16)va[cq*2+1]), fb1 = bf2f((u16)vb[cq*2+1]), fc1 = bf2f((u16)vc[cq*2+1]);
      float v0 = fmaf(wc, fc0, fmaf(wb, fb0, wa*fa0));
      float v1 = fmaf(wc, fc1, fmaf(wb, fb1, wa*fa1));
      pk[cq] = (u32)f2bf(v0) | ((u32)f2bf(v1)<<16);
    }
    *(u32x4*)(Ft + ((size_t)b*N_ + pid)*512 + ct*8) = pk;
  }
}

// ---------------- K2b: transpose unknow_feats -> Ft[:, :, 256:512] ----------------
__global__ __launch_bounds__(256) void k2b_transpose_uf(
    const void* uf, const int* __restrict__ flagp, u16* __restrict__ Ft){
  __shared__ u16 Ls[64*72];
  int bx = blockIdx.x, cy = blockIdx.y, b = blockIdx.z, t = threadIdx.x;
  int f = flagp[0];
  {
    int n = t & 63, cg = t >> 6;
    for (int i=0; i<16; i++){
      int c = cg*16 + i;
      Ls[n*72 + c] = f2bf(ldf(uf, ((size_t)b*DD + cy*64 + c)*N_ + bx*64 + n, f));
    }
  }
  __syncthreads();
  int nl = t>>2, cc = t&3;
  u16* dst = Ft + ((size_t)b*N_ + bx*64 + nl)*512 + 256 + cy*64 + cc*16;
  *(u32x4*)dst     = *(const u32x4*)(Ls + nl*72 + cc*16);
  *(u32x4*)(dst+8) = *(const u32x4*)(Ls + nl*72 + cc*16 + 8);
}

// ---------------- K3/K4: MFMA GEMM, BK=64, global_load_lds + XOR-swizzled LDS ----------------
// LDS layout: 16B chunk (row R, chunk C) lives at slot R*8 + (C^(R&7)).
// Staging slot s -> global chunk (row=s>>3, k8=(s&7)^(row&7)) keeps the DMA
// destination contiguous (lane*16) while fragment reads are conflict-free.
__global__ __launch_bounds__(256) void gemm_bn_relu(
    const u16* __restrict__ W, const u16* __restrict__ Fin,
    const float* __restrict__ consts, int sc_off, int sh_off,
    u16* __restrict__ Out, int K){
  __shared__ u16 SM[17408]; // As(8192)+Bs(8192) u16 in K-loop; Cs(128x136) in epilogue
  u16* As = SM; u16* Bs = SM + 8192;
  int b = blockIdx.z, ot = blockIdx.y*128, nt = blockIdx.x*128;
  int t = threadIdx.x, wave = t>>6, lane = t&63, ln = lane&15, quad = lane>>4;
  int wo = (wave&1)*64, wn = (wave>>1)*64;
  f32x4 acc[4][4];
  #pragma unroll
  for (int i=0;i<4;i++)
    #pragma unroll
    for (int j=0;j<4;j++) acc[i][j] = (f32x4)0.f;
  const u16* Wp = W + (size_t)ot*K;
  const u16* Fp = Fin + ((size_t)b*N_ + nt)*K;
  for (int kk=0; kk<K; kk+=64){
    #pragma unroll
    for (int i=0;i<4;i++){
      int c = wave*256 + i*64 + lane;          // chunk slot 0..1023
      int r = c>>3, k8 = (c&7) ^ (r&7);
      const u16* gA = Wp + (size_t)r*K + kk + k8*8;
      const u16* gB = Fp + (size_t)r*K + kk + k8*8;
      gl_lds16(gA, As + (size_t)(wave*256 + i*64)*8);
      gl_lds16(gB, Bs + (size_t)(wave*256 + i*64)*8);
    }
    __syncthreads();
    #pragma unroll
    for (int kh=0; kh<2; kh++){
      short8 af[4], bfr[4];
      #pragma unroll
      for (int i=0;i<4;i++){
        int R = wo + i*16 + ln, C = kh*4 + quad;
        af[i] = *(const short8*)(As + (size_t)(R*8 + (C^(R&7)))*8);
      }
      #pragma unroll
      for (int j=0;j<4;j++){
        int R = wn + j*16 + ln, C = kh*4 + quad;
        bfr[j] = *(const short8*)(Bs + (size_t)(R*8 + (C^(R&7)))*8);
      }
      #pragma unroll
      for (int i=0;i<4;i++)
        #pragma unroll
        for (int j=0;j<4;j++)
          acc[i][j] = __builtin_amdgcn_mfma_f32_16x16x32_bf16(af[i], bfr[j], acc[i][j], 0,0,0);
    }
    __syncthreads();
  }
  u16* Cs = SM; // stride 136
  #pragma unroll
  for (int i=0;i<4;i++){
    #pragma unroll
    for (int r=0;r<4;r++){
      int ol = wo + i*16 + quad*4 + r;
      float sc = consts[sc_off + ot + ol], sh = consts[sh_off + ot + ol];
      #pragma unroll
      for (int j=0;j<4;j++){
        float v = fmaxf(fmaf(acc[i][j][r], sc, sh), 0.f);
        Cs[(wn + j*16 + ln)*136 + ol] = f2bf(v);
      }
    }
  }
  __syncthreads();
  int nl = t>>1, half = t&1;
  u16* dst = Out + ((size_t)b*N_ + nt + nl)*256 + ot + half*64;
  const u16* srcr = Cs + nl*136 + half*64;
  #pragma unroll
  for (int c=0;c<8;c++)
    *(u32x4*)(dst + c*8) = *(const u32x4*)(srcr + c*8);
}

// ---------------- K5: encoding partials ----------------
__global__ __launch_bounds__(256) void k5_enc_partial(
    const u16* __restrict__ X, const u16* __restrict__ cw,
    const float* __restrict__ consts, float* __restrict__ Epart){
  __shared__ u16 Xs[64*264];
  __shared__ float A_lds[64*32];
  __shared__ float xn2s[64];
  int g = blockIdx.x, b = blockIdx.y, t = threadIdx.x;
  int wave = t>>6, lane = t&63, ln = lane&15, quad = lane>>4;
  int tk = t>>3, tg = t&7;
  float accE[32];
  #pragma unroll
  for (int p=0;p<32;p++) accE[p]=0.f;
  float asum = 0.f;
  float c2v0 = consts[C2OFF + ln], c2v1 = consts[C2OFF + 16 + ln];
  float sv0  = consts[SOFF + ln],  sv1  = consts[SOFF + 16 + ln];
  for (int tt=0; tt<2; tt++){
    int n0 = (g*2+tt)*64;
    const u16* Xp = X + ((size_t)b*N_ + n0)*256;
    #pragma unroll
    for (int i=0;i<8;i++){
      int ch = t + i*256;
      int r = ch>>5, kc = (ch&31)*8;
      *(u32x4*)(Xs + r*264 + kc) = *(const u32x4*)(Xp + r*256 + kc);
    }
    __syncthreads();
    if (t < 64){
      const u16* row = Xs + t*264;
      float s = 0.f;
      for (int d=0; d<256; d+=8){
        short8 xv = *(const short8*)(row + d);
        #pragma unroll
        for (int q=0;q<8;q++){ float x = bf2f((u16)xv[q]); s = fmaf(x,x,s); }
      }
      xn2s[t] = s;
    }
    __syncthreads();
    f32x4 pj0 = (f32x4)0.f, pj1 = (f32x4)0.f;
    const u16* xrow = Xs + (wave*16 + ln)*264;
    #pragma unroll
    for (int kk=0; kk<256; kk+=32){
      short8 a   = *(const short8*)(xrow + kk + quad*8);
      short8 bf0 = *(const short8*)(cw + (size_t)ln*256 + kk + quad*8);
      short8 bf1 = *(const short8*)(cw + (size_t)(16+ln)*256 + kk + quad*8);
      pj0 = __builtin_amdgcn_mfma_f32_16x16x32_bf16(a, bf0, pj0, 0,0,0);
      pj1 = __builtin_amdgcn_mfma_f32_16x16x32_bf16(a, bf1, pj1, 0,0,0);
    }
    #pragma unroll
    for (int r=0;r<4;r++){
      int nl = wave*16 + quad*4 + r;
      float xv = xn2s[nl];
      float v0 = sv0 * __fadd_rn(__fsub_rn(xv, __fmul_rn(2.f,pj0[r])), c2v0);
      float v1 = sv1 * __fadd_rn(__fsub_rn(xv, __fmul_rn(2.f,pj1[r])), c2v1);
      float mx = fmaxf(v0,v1);
      #pragma unroll
      for (int d=1; d<16; d<<=1) mx = fmaxf(mx, __shfl_xor(mx, d, 64));
      float e0 = __expf(v0-mx), e1 = __expf(v1-mx);
      float es = e0+e1;
      #pragma unroll
      for (int d=1; d<16; d<<=1) es += __shfl_xor(es, d, 64);
      float inv = 1.f/es;
      A_lds[nl*32 + ln]      = e0*inv;
      A_lds[nl*32 + 16 + ln] = e1*inv;
    }
    __syncthreads();
    #pragma unroll 2
    for (int n=0; n<64; n++){
      float a = A_lds[n*32 + tk];
      asum += a;
      const u16* xr = Xs + n*264 + tg*32;
      #pragma unroll
      for (int p8=0; p8<4; p8++){
        u32x4 xv = *(const u32x4*)(xr + p8*8);
        #pragma unroll
        for (int q=0; q<4; q++){
          u32 w = xv[q];
          float lo = __uint_as_float(w<<16);
          float hi = __uint_as_float(w & 0xffff0000u);
          accE[p8*8 + q*2]   = fmaf(a, lo, accE[p8*8 + q*2]);
          accE[p8*8 + q*2+1] = fmaf(a, hi, accE[p8*8 + q*2+1]);
        }
      }
    }
    __syncthreads();
  }
  int slab = b*64 + g;
  float* Ed = Epart + (size_t)slab*8224 + (size_t)tk*257;
  #pragma unroll
  for (int p=0;p<32;p++) Ed[tg*32 + p] = accE[p];
  if (tg==0) Ed[256] = asum;
}

// ---------------- K5b: reduce slabs, subtract asum*cw, relu ----------------
__global__ __launch_bounds__(256) void k5b_reduce(
    const float* __restrict__ Epart, const u16* __restrict__ cw, float* __restrict__ Erelu){
  int id = blockIdx.x*256 + threadIdx.x;
  int d = id & 255, k = (id>>8)&31, b = id>>13;
  float s = 0.f, as = 0.f;
  for (int sl=0; sl<64; sl++){
    const float* Ep = Epart + ((size_t)(b*64+sl))*8224 + (size_t)k*257;
    s  += Ep[d];
    as += Ep[256];
  }
  float cv = bf2f(cw[k*256+d]);
  Erelu[(size_t)b*8192 + k*256 + d] = fmaxf(s - as*cv, 0.f);
}

// ---------------- K6a: per-batch L2 norm ----------------
__global__ __launch_bounds__(256) void k6a_norm(
    const float* __restrict__ Erelu, float* __restrict__ consts){
  __shared__ float red[256];
  int b = blockIdx.x, t = threadIdx.x;
  float s = 0.f;
  for (int i=0;i<32;i++){ float e = Erelu[(size_t)b*8192 + i*256 + t]; s = fmaf(e,e,s); }
  red[t] = s; __syncthreads();
  for (int w=128; w>0; w>>=1){ if (t<w) red[t] += red[t+w]; __syncthreads(); }
  if (t==0) consts[RNOFF + b] = 1.f/fmaxf(__fsqrt_rn(red[0]), 1e-12f);
}

// ---------------- K6b: linear partial dots ----------------
__global__ __launch_bounds__(256) void k6b_partial(
    const float* __restrict__ Erelu, const void* lw, const int* __restrict__ flagp,
    float* __restrict__ partials){
  __shared__ float Er[256];
  int kc = blockIdx.x, b = blockIdx.y, t = threadIdx.x;
  int f = flagp[0];
  Er[t] = Erelu[(size_t)b*8192 + kc*256 + t];
  __syncthreads();
  float s = 0.f;
  if (f){
    const float* lwp = (const float*)lw + (size_t)t*8192 + kc*256;
    for (int p=0; p<256; p+=4){
      f32x4 v = *(const f32x4*)(lwp + p);
      #pragma unroll
      for (int q=0;q<4;q++) s = fmaf(Er[p+q], v[q], s);
    }
  } else {
    const u16* lwp = (const u16*)lw + (size_t)t*8192 + kc*256;
    for (int p=0; p<256; p+=8){
      u32x4 v = *(const u32x4*)(lwp + p);
      #pragma unroll
      for (int q=0;q<4;q++){
        u32 w = v[q];
        s = fmaf(Er[p+q*2],   __uint_as_float(w<<16), s);
        s = fmaf(Er[p+q*2+1], __uint_as_float(w & 0xffff0000u), s);
      }
    }
  }
  partials[((size_t)b*32 + kc)*256 + t] = s;
}

// ---------------- K6c: ctx = sigmoid(rnorm*dot + bias) ----------------
__global__ __launch_bounds__(256) void k6c_ctx(
    const float* __restrict__ partials, const float* __restrict__ consts,
    const void* lb, const int* __restrict__ flagp, float* __restrict__ ctx){
  int b = blockIdx.x, t = threadIdx.x;
  int f = flagp[0];
  float s = 0.f;
  for (int kc=0; kc<32; kc++) s += partials[((size_t)b*32+kc)*256 + t];
  float x = fmaf(consts[RNOFF+b], s, ldf(lb,t,f));
  ctx[b*256 + t] = 1.f/(1.f + __expf(-x));
}

// ---------------- K7: out[b][o][n] = ht[b][n][o] * ctx[b][o] ----------------
__global__ __launch_bounds__(256) void k7_out(
    const u16* __restrict__ ht, const float* __restrict__ ctx,
    const int* __restrict__ flagp, void* out){
  __shared__ u16 Ls[64*72];
  int bx = blockIdx.x, oy = blockIdx.y, b = blockIdx.z, t = threadIdx.x;
  int f = flagp[0];
  {
    int nl = t>>2, oc = t&3;
    const u16* src = ht + ((size_t)b*N_ + bx*64 + nl)*256 + oy*64 + oc*16;
    *(u32x4*)(Ls + nl*72 + oc*16)     = *(const u32x4*)src;
    *(u32x4*)(Ls + nl*72 + oc*16 + 8) = *(const u32x4*)(src + 8);
  }
  __syncthreads();
  int ol = t>>2, nc = t&3;
  float cv = ctx[b*256 + oy*64 + ol];
  size_t dstoff = ((size_t)b*DD + oy*64 + ol)*N_ + bx*64 + nc*16;
  if (f){
    float* dst = (float*)out + dstoff;
    #pragma unroll
    for (int wq=0; wq<4; wq++){
      f32x4 v;
      #pragma unroll
      for (int q=0;q<4;q++) v[q] = bf2f(Ls[(nc*16 + wq*4 + q)*72 + ol]) * cv;
      *(f32x4*)(dst + wq*4) = v;
    }
  } else {
    u32 words[8];
    #pragma unroll
    for (int wq=0; wq<8; wq++){
      float v0 = bf2f(Ls[(nc*16 + wq*2)*72 + ol]) * cv;
      float v1 = bf2f(Ls[(nc*16 + wq*2+1)*72 + ol]) * cv;
      words[wq] = (u32)f2bf(v0) | ((u32)f2bf(v1)<<16);
    }
    u16* dst = (u16*)out + dstoff;
    u32x4 w0 = {words[0],words[1],words[2],words[3]};
    u32x4 w1 = {words[4],words[5],words[6],words[7]};
    *(u32x4*)dst     = w0;
    *(u32x4*)(dst+8) = w1;
  }
}

extern "C" void kernel_launch(void* const* d_in, const int* in_sizes, int n_in,
                              void* d_out, int out_size, void* d_ws, size_t ws_size,
                              hipStream_t stream){
  const void* unknown = d_in[0];
  const void* known   = d_in[1];
  const void* uf      = d_in[2];
  const void* kf      = d_in[3];
  const void* w1      = d_in[4];
  const void* cb1     = d_in[5];
  const void* g1      = d_in[6];
  const void* be1     = d_in[7];
  const void* m1      = d_in[8];
  const void* v1      = d_in[9];
  const void* w2      = d_in[10];
  const void* cb2     = d_in[11];
  const void* g2      = d_in[12];
  const void* be2     = d_in[13];
  const void* m2      = d_in[14];
  const void* v2      = d_in[15];
  const void* cw      = d_in[16];
  const void* es      = d_in[17];
  const void* lw      = d_in[18];
  const void* lb      = d_in[19];

  char* ws = (char*)d_ws;
  int*   idx3  = (int*)(ws + OFF_IDX3);
  float* w3    = (float*)(ws + OFF_W3);
  u16*   Ft    = (u16*)(ws + OFF_FT);
  u16*   ht    = Ft;                       // alias: Ft dead after GEMM1 consumes it
  u16*   h1t   = (u16*)(ws + OFF_H1T);
  float* Epart = (float*)(ws + OFF_H1T);   // alias: h1t dead after GEMM2
  float* Erelu    = (float*)(ws + OFF_ERELU);
  float* partials = (float*)(ws + OFF_PART);
  float* consts   = (float*)(ws + OFF_CONSTS);
  float* ctx      = (float*)(ws + OFF_CTX);
  u16*   W1d   = (u16*)(ws + OFF_W1D);
  u16*   W2d   = (u16*)(ws + OFF_W2D);
  u16*   CWd   = (u16*)(ws + OFF_CWD);
  int*   flagp = (int*)(ws + OFF_FLAG);

  k_detect<<<1, 256, 0, stream>>>(v1, flagp);
  k_convert<<<800, 256, 0, stream>>>(w1, w2, cw, flagp, W1d, W2d, CWd);
  k0_setup<<<1, 256, 0, stream>>>(cb1,g1,be1,m1,v1, cb2,g2,be2,m2,v2, CWd, es, flagp, consts);
  k1_three_nn<<<dim3(64,8), 256, 0, stream>>>(unknown, known, flagp, idx3, w3);
  k2_interp<<<dim3(32,4,8), 256, 0, stream>>>(kf, idx3, w3, flagp, Ft);
  k2b_transpose_uf<<<dim3(128,4,8), 256, 0, stream>>>(uf, flagp, Ft);
  gemm_bn_relu<<<dim3(64,2,8), 256, 0, stream>>>(W1d, Ft,  consts, SC1, SH1, h1t, 512);
  gemm_bn_relu<<<dim3(64,2,8), 256, 0, stream>>>(W2d, h1t, consts, SC2, SH2, ht,  256);
  k5_enc_partial<<<dim3(64,8), 256, 0, stream>>>(ht, CWd, consts, Epart);
  k5b_reduce<<<256, 256, 0, stream>>>(Epart, CWd, Erelu);
  k6a_norm<<<8, 256, 0, stream>>>(Erelu, consts);
  k6b_partial<<<dim3(32,8), 256, 0, stream>>>(Erelu, lw, flagp, partials);
  k6c_ctx<<<8, 256, 0, stream>>>(partials, consts, lb, flagp, ctx);
  k7_out<<<dim3(128,4,8), 256, 0, stream>>>(ht, ctx, flagp, d_out);
}